// Round 5
// baseline (679.485 us; speedup 1.0000x reference)
//
#include <hip/hip_runtime.h>
#include <math.h>

typedef _Float16 f16;
typedef _Float16 f16x8 __attribute__((ext_vector_type(8)));
typedef _Float16 f16x4 __attribute__((ext_vector_type(4)));
typedef float f32x4 __attribute__((ext_vector_type(4)));

#define NROWS 12288
#define NFEAT 4096
#define DDIM  256
#define KDIM  1000
#define KPAD  1024
#define NBLK  768

// workspace layout (bytes)
static const size_t OFF_A16 = 0;           // 12288*256 f16
static const size_t OFF_BF  = 6291456;     // 1024*256 f16
static const size_t OFF_E16 = 6815744;     // 12288*1024 f16
static const size_t OFF_S   = 31981568;    // 3*1024 f32
static const size_t OFF_BAR = 31993856;    // 4 u32 barrier counters

__device__ inline float wsum(float v) {
#pragma unroll
    for (int m = 32; m >= 1; m >>= 1) v += __shfl_xor(v, m, 64);
    return v;
}

// software grid barrier: safe because grid(768) == exact co-resident capacity
// (256 CU x 3 blocks: LDS 3x34.8KB=104KB<160KB, VGPR capped by launch_bounds).
// Mirrors __ockl_grid_sync: fence -> atomic arrive -> spin acquire -> s_barrier.
__device__ inline void gridbar(unsigned* bar) {
    __syncthreads();
    if (threadIdx.x == 0) {
        __threadfence();
        __hip_atomic_fetch_add(bar, 1u, __ATOMIC_ACQ_REL, __HIP_MEMORY_SCOPE_AGENT);
        while (__hip_atomic_load(bar, __ATOMIC_ACQUIRE, __HIP_MEMORY_SCOPE_AGENT) < NBLK)
            __builtin_amdgcn_s_sleep(8);
        __threadfence();
    }
    __syncthreads();
}

// rowpass phase: r[k]=1/(1000*Sin[k]); c[b]=1/(12288*dot(E[b,:],r));
// Sout[k] += E[b,k]*c[b]. 16 rows/block, lane owns fixed 16-col slice.
__device__ inline void rowpass_phase(const f16* __restrict__ E16,
                                     const float* Sin, float* Sout,
                                     char* smem, int tid, int bid) {
    float* rl = (float*)smem;                             // 4 KB
    float (*cols4)[KPAD] = (float(*)[KPAD])(smem + 4096); // 16 KB
    for (int n = tid; n < KPAD; n += 256)
        rl[n] = (n < KDIM) ? 1.0f / (1000.0f * Sin[n]) : 0.0f;
    __syncthreads();
    int wave = tid >> 6, lane = tid & 63;
    int n0 = lane * 16;
    float rv[16];
#pragma unroll
    for (int i = 0; i < 16; ++i) rv[i] = rl[n0 + i];
    float ca[16];
#pragma unroll
    for (int i = 0; i < 16; ++i) ca[i] = 0.f;
    int rowbase = bid * 16 + wave * 4;
    for (int j = 0; j < 4; ++j) {
        const f16* er = E16 + (size_t)(rowbase + j) * KPAD + n0;
        f16x8 e0 = *(const f16x8*)er;
        f16x8 e1 = *(const f16x8*)(er + 8);
        float ev[16];
#pragma unroll
        for (int i = 0; i < 8; ++i) { ev[i] = (float)e0[i]; ev[8 + i] = (float)e1[i]; }
        float p = 0.f;
#pragma unroll
        for (int i = 0; i < 16; ++i) p += ev[i] * rv[i];
        p = wsum(p);
        float c = 1.0f / (12288.0f * p);
#pragma unroll
        for (int i = 0; i < 16; ++i) ca[i] += ev[i] * c;
    }
#pragma unroll
    for (int i = 0; i < 16; ++i) {
        int idx = (i + lane) & 15;
        cols4[wave][n0 + idx] = ca[idx];
    }
    __syncthreads();
    for (int n = tid; n < KDIM; n += 256) {
        float s = cols4[0][n] + cols4[1][n] + cols4[2][n] + cols4[3][n];
        atomicAdd(&Sout[n], s);
    }
}

// ---------------------------------------------------------------------------
__global__ __launch_bounds__(256, 3)
void fused_k(const float* __restrict__ feats, const float* __restrict__ head,
             const float* __restrict__ queue, f16* __restrict__ A16,
             f16* __restrict__ Bf, f16* __restrict__ E16,
             float* S, unsigned* bar, float* __restrict__ out) {
    __shared__ __align__(16) char smem[34816];
    int tid = threadIdx.x, bid = blockIdx.x;
    int wave = tid >> 6, lane = tid & 63;
    float* S0 = S;
    float* S1 = S + KPAD;
    float* S2 = S + 2 * KPAD;

    // ===== P0: prep — row norms -> A16; head norm+transpose -> Bf; zero S =====
    {
#pragma unroll
        for (int j = 0; j < 4; ++j) {
            int row = bid * 16 + j * 4 + wave;
            const float* src = (row < NFEAT) ? feats + (size_t)row * DDIM
                                             : queue + (size_t)(row - NFEAT) * DDIM;
            float4 v = *(const float4*)(src + lane * 4);
            float s = wsum(v.x * v.x + v.y * v.y + v.z * v.z + v.w * v.w);
            float inv = 1.0f / sqrtf(fmaxf(s, 1e-24f));
            f16x4 o = { (f16)(v.x * inv), (f16)(v.y * inv), (f16)(v.z * inv), (f16)(v.w * inv) };
            *(f16x4*)(A16 + (size_t)row * DDIM + lane * 4) = o;
        }
        if (bid < 16) {
            float* rin = (float*)smem;
            int kb = bid * 16;
            for (int j = 0; j < 4; ++j) {
                int k = kb + wave * 4 + j;
                const float* hr = head + (size_t)k * KDIM;
                float s = 0.f;
                for (int n = lane; n < KDIM; n += 64) { float v = hr[n]; s += v * v; }
                s = wsum(s);
                if (lane == 0) rin[wave * 4 + j] = 1.0f / sqrtf(fmaxf(s, 1e-24f));
            }
            __syncthreads();
            float r[16];
#pragma unroll
            for (int i = 0; i < 16; ++i) r[i] = rin[i];
            for (int n = tid; n < KDIM; n += 256) {
                f16 tmp[16];
#pragma unroll
                for (int i = 0; i < 16; ++i)
                    tmp[i] = (f16)(head[(size_t)(kb + i) * KDIM + n] * r[i]);
                f16* dst = Bf + (size_t)n * DDIM + kb;
                *(uint4*)(dst)     = *(const uint4*)(tmp);
                *(uint4*)(dst + 8) = *(const uint4*)(tmp + 8);
            }
        } else if (bid == 16) {
            for (int i = tid; i < 3 * KPAD; i += 256) S[i] = 0.f;
        }
    }
    gridbar(bar + 0);

    // ===== P1: MFMA gemm + exp + colsum -> S0; E16 store =====
    {
        f16 (*Es)[136] = (f16(*)[136])smem;
        int bx = bid & 7, by = bid >> 3;
        int lm = lane & 15, q = lane >> 4;
        int row0 = by * 128, col0 = bx * 128;
        int wm = (wave >> 1) * 64, wn = (wave & 1) * 64;
        const f16* Ab = A16 + (size_t)(row0 + wm + lm) * DDIM + q * 8;
        const f16* Bb = Bf  + (size_t)(col0 + wn + lm) * DDIM + q * 8;

        f32x4 acc[4][4];
#pragma unroll
        for (int i = 0; i < 4; ++i)
#pragma unroll
            for (int j = 0; j < 4; ++j) acc[i][j] = (f32x4){0.f, 0.f, 0.f, 0.f};

#pragma unroll
        for (int kt = 0; kt < DDIM; kt += 32) {
            f16x8 a[4], b[4];
#pragma unroll
            for (int ms = 0; ms < 4; ++ms) a[ms] = *(const f16x8*)(Ab + (size_t)ms * 16 * DDIM + kt);
#pragma unroll
            for (int ns = 0; ns < 4; ++ns) b[ns] = *(const f16x8*)(Bb + (size_t)ns * 16 * DDIM + kt);
#pragma unroll
            for (int ms = 0; ms < 4; ++ms)
#pragma unroll
                for (int ns = 0; ns < 4; ++ns)
                    acc[ms][ns] = __builtin_amdgcn_mfma_f32_16x16x32_f16(a[ms], b[ns], acc[ms][ns], 0, 0, 0);
        }

        float colp[4] = {0.f, 0.f, 0.f, 0.f};
#pragma unroll
        for (int ms = 0; ms < 4; ++ms) {
#pragma unroll
            for (int ns = 0; ns < 4; ++ns) {
                int gc = col0 + wn + ns * 16 + lm;
                bool ok = gc < KDIM;
#pragma unroll
                for (int r = 0; r < 4; ++r) {
                    float e = ok ? __expf(acc[ms][ns][r] * 20.0f) : 0.0f;
                    colp[ns] += e;
                    Es[wm + ms * 16 + q * 4 + r][wn + ns * 16 + lm] = (f16)e;
                }
            }
        }
#pragma unroll
        for (int ns = 0; ns < 4; ++ns) {
            float v = colp[ns];
            v += __shfl_xor(v, 16, 64);
            v += __shfl_xor(v, 32, 64);
            if (lane < 16) atomicAdd(&S0[col0 + wn + ns * 16 + lane], v);
        }
        __syncthreads();
        int r = tid >> 1, half = tid & 1;
        const f16* src = &Es[r][half * 64];
        f16* dst = E16 + (size_t)(row0 + r) * KPAD + col0 + half * 64;
#pragma unroll
        for (int i = 0; i < 8; ++i)
            *(uint4*)(dst + i * 8) = *(const uint4*)(src + i * 8);
    }
    gridbar(bar + 1);

    // ===== P2, P3: two Sinkhorn row/col passes =====
    rowpass_phase(E16, S0, S1, smem, tid, bid);
    gridbar(bar + 2);
    rowpass_phase(E16, S1, S2, smem, tid, bid);
    gridbar(bar + 3);

    // ===== P4: output rows < 4096 =====
    {
        float* rl = (float*)smem;
        for (int n = tid; n < KPAD; n += 256)
            rl[n] = (n < KDIM) ? 1.0f / (1000.0f * S2[n]) : 0.0f;
        __syncthreads();
        int n0 = lane * 16;
        float rv[16];
#pragma unroll
        for (int i = 0; i < 16; ++i) rv[i] = rl[n0 + i];
        int w = bid * 4 + wave;
        for (int row = w; row < NFEAT; row += 3072) {
            const f16* er = E16 + (size_t)row * KPAD + n0;
            f16x8 e0 = *(const f16x8*)er;
            f16x8 e1 = *(const f16x8*)(er + 8);
            float wv[16];
            float p = 0.f;
#pragma unroll
            for (int i = 0; i < 8; ++i) {
                wv[i] = (float)e0[i] * rv[i];
                wv[8 + i] = (float)e1[i] * rv[8 + i];
            }
#pragma unroll
            for (int i = 0; i < 16; ++i) p += wv[i];
            p = wsum(p);
            float inv = 1.0f / p;
            float* orow = out + (size_t)row * KDIM;
#pragma unroll
            for (int i = 0; i < 16; i += 4) {
                int n = n0 + i;
                if (n + 3 < KDIM) {
                    float4 o = { wv[i] * inv, wv[i + 1] * inv, wv[i + 2] * inv, wv[i + 3] * inv };
                    *(float4*)(orow + n) = o;
                } else {
#pragma unroll
                    for (int t = 0; t < 4; ++t)
                        if (n + t < KDIM) orow[n + t] = wv[i + t] * inv;
                }
            }
        }
    }
}

// ---------------------------------------------------------------------------
extern "C" void kernel_launch(void* const* d_in, const int* in_sizes, int n_in,
                              void* d_out, int out_size, void* d_ws, size_t ws_size,
                              hipStream_t stream) {
    (void)in_sizes; (void)n_in; (void)out_size; (void)ws_size;
    const float* feats = (const float*)d_in[0];   // [4096,256]
    const float* head  = (const float*)d_in[1];   // [256,1000]
    const float* queue = (const float*)d_in[2];   // [8192,256]
    float* out = (float*)d_out;                   // [4096,1000]

    char* ws = (char*)d_ws;
    f16*      A16 = (f16*)(ws + OFF_A16);
    f16*      Bf  = (f16*)(ws + OFF_BF);
    f16*      E16 = (f16*)(ws + OFF_E16);
    float*    S   = (float*)(ws + OFF_S);
    unsigned* bar = (unsigned*)(ws + OFF_BAR);

    // ws is re-poisoned to 0xAA before every timed launch: barrier counters
    // must be zeroed on-stream each call.
    hipMemsetAsync(bar, 0, 4 * sizeof(unsigned), stream);
    fused_k<<<NBLK, 256, 0, stream>>>(feats, head, queue, A16, Bf, E16, S, bar, out);
}

// Round 6
// 300.918 us; speedup vs baseline: 2.2580x; 2.2580x over previous
//
#include <hip/hip_runtime.h>
#include <math.h>

typedef _Float16 f16;
typedef _Float16 f16x8 __attribute__((ext_vector_type(8)));
typedef _Float16 f16x4 __attribute__((ext_vector_type(4)));
typedef float f32x4 __attribute__((ext_vector_type(4)));

#define NROWS 12288
#define NFEAT 4096
#define DDIM  256
#define KDIM  1000
#define KPAD  1024

// workspace layout (bytes)
static const size_t OFF_A16 = 0;           // 12288*256 f16 = 6,291,456
static const size_t OFF_BF  = 6291456;     // 1024*256 f16  =   524,288
static const size_t OFF_E16 = 6815744;     // 12288*1024 f16= 25,165,824
static const size_t OFF_P0  = 31981568;    // 96*1024 f32   =   393,216
static const size_t OFF_P1  = 32374784;    // 256*1024 f32  = 1,048,576
static const size_t OFF_P2  = 33423360;    // 256*1024 f32  = 1,048,576
static const size_t OFF_S   = 34471936;    // 3*1024 f32

__device__ inline float wsum(float v) {
#pragma unroll
    for (int m = 32; m >= 1; m >>= 1) v += __shfl_xor(v, m, 64);
    return v;
}

// ---------------------------------------------------------------------------
// prep: [0,3072) feats/queue row norms -> A16 (4 rows/block)
//       [3072,3088) head: 16 rows/block -> rinv + transposed f16 Bf
__global__ __launch_bounds__(256)
void prep_k(const float* __restrict__ feats, const float* __restrict__ queue,
            const float* __restrict__ head, f16* __restrict__ A16,
            f16* __restrict__ Bf) {
    int b = blockIdx.x, tid = threadIdx.x;
    int wave = tid >> 6, lane = tid & 63;
    if (b < 3072) {
        int row = b * 4 + wave;
        const float* src = (row < NFEAT) ? feats + (size_t)row * DDIM
                                         : queue + (size_t)(row - NFEAT) * DDIM;
        float4 v = *(const float4*)(src + lane * 4);
        float s = wsum(v.x * v.x + v.y * v.y + v.z * v.z + v.w * v.w);
        float inv = 1.0f / sqrtf(fmaxf(s, 1e-24f));
        f16x4 o = { (f16)(v.x * inv), (f16)(v.y * inv), (f16)(v.z * inv), (f16)(v.w * inv) };
        *(f16x4*)(A16 + (size_t)row * DDIM + lane * 4) = o;
    } else {
        __shared__ float rin[16];
        int kb = (b - 3072) * 16;
        for (int j = 0; j < 4; ++j) {
            int k = kb + wave * 4 + j;
            const float* hr = head + (size_t)k * KDIM;
            float s = 0.f;
            for (int n = lane; n < KDIM; n += 64) { float v = hr[n]; s += v * v; }
            s = wsum(s);
            if (lane == 0) rin[wave * 4 + j] = 1.0f / sqrtf(fmaxf(s, 1e-24f));
        }
        __syncthreads();
        float r[16];
#pragma unroll
        for (int i = 0; i < 16; ++i) r[i] = rin[i];
        for (int n = tid; n < KDIM; n += 256) {
            f16 tmp[16];
#pragma unroll
            for (int i = 0; i < 16; ++i)
                tmp[i] = (f16)(head[(size_t)(kb + i) * KDIM + n] * r[i]);
            f16* dst = Bf + (size_t)n * DDIM + kb;
            *(uint4*)(dst)     = *(const uint4*)(tmp);
            *(uint4*)(dst + 8) = *(const uint4*)(tmp + 8);
        }
    }
}

// ---------------------------------------------------------------------------
// MFMA GEMM + exp + f16 E store + colsum partial -> P0[by][col] (NO atomics).
__global__ __launch_bounds__(256, 3)
void gemm_exp_k(const f16* __restrict__ A16, const f16* __restrict__ Bf,
                f16* __restrict__ E16, float* __restrict__ P0) {
    __shared__ __align__(16) char smem[34816];
    f16 (*Es)[136] = (f16(*)[136])smem;
    int tid = threadIdx.x;
    int wave = tid >> 6, lane = tid & 63;
    int lm = lane & 15, q = lane >> 4;
    int row0 = blockIdx.y * 128, col0 = blockIdx.x * 128;
    int wm = (wave >> 1) * 64, wn = (wave & 1) * 64;
    const f16* Ab = A16 + (size_t)(row0 + wm + lm) * DDIM + q * 8;
    const f16* Bb = Bf  + (size_t)(col0 + wn + lm) * DDIM + q * 8;

    f32x4 acc[4][4];
#pragma unroll
    for (int i = 0; i < 4; ++i)
#pragma unroll
        for (int j = 0; j < 4; ++j) acc[i][j] = (f32x4){0.f, 0.f, 0.f, 0.f};

#pragma unroll
    for (int kt = 0; kt < DDIM; kt += 32) {
        f16x8 a[4], b[4];
#pragma unroll
        for (int ms = 0; ms < 4; ++ms) a[ms] = *(const f16x8*)(Ab + (size_t)ms * 16 * DDIM + kt);
#pragma unroll
        for (int ns = 0; ns < 4; ++ns) b[ns] = *(const f16x8*)(Bb + (size_t)ns * 16 * DDIM + kt);
#pragma unroll
        for (int ms = 0; ms < 4; ++ms)
#pragma unroll
            for (int ns = 0; ns < 4; ++ns)
                acc[ms][ns] = __builtin_amdgcn_mfma_f32_16x16x32_f16(a[ms], b[ns], acc[ms][ns], 0, 0, 0);
    }

    float colp[4] = {0.f, 0.f, 0.f, 0.f};
#pragma unroll
    for (int ms = 0; ms < 4; ++ms) {
#pragma unroll
        for (int ns = 0; ns < 4; ++ns) {
            int gc = col0 + wn + ns * 16 + lm;
            bool ok = gc < KDIM;
#pragma unroll
            for (int r = 0; r < 4; ++r) {
                float e = ok ? __expf(acc[ms][ns][r] * 20.0f) : 0.0f;
                colp[ns] += e;
                Es[wm + ms * 16 + q * 4 + r][wn + ns * 16 + lm] = (f16)e;
            }
        }
    }
    // sum over q (rows within the wave's 64-row half)
#pragma unroll
    for (int ns = 0; ns < 4; ++ns) {
        colp[ns] += __shfl_xor(colp[ns], 16, 64);
        colp[ns] += __shfl_xor(colp[ns], 32, 64);
    }
    __syncthreads();
    // coalesced f16 store of the block's 128x128 tile
    {
        int r = tid >> 1, half = tid & 1;
        const f16* src = &Es[r][half * 64];
        f16* dst = E16 + (size_t)(row0 + r) * KPAD + col0 + half * 64;
#pragma unroll
        for (int i = 0; i < 8; ++i)
            *(uint4*)(dst + i * 8) = *(const uint4*)(src + i * 8);
    }
    __syncthreads();            // all Es reads done; reuse smem for colsum
    float* cred = (float*)smem; // 128 floats
    if (tid < 128) cred[tid] = 0.f;
    __syncthreads();
    if (lane < 16) {
#pragma unroll
        for (int ns = 0; ns < 4; ++ns)
            atomicAdd(&cred[wn + ns * 16 + lane], colp[ns]);   // LDS atomic, 2-deep
    }
    __syncthreads();
    if (tid < 128) P0[(size_t)blockIdx.y * KPAD + col0 + tid] = cred[tid];
}

// ---------------------------------------------------------------------------
// redS: S[k] = sum_{t<T} P[t*KPAD + k].  grid(4) x 256 threads.
__global__ __launch_bounds__(256)
void redS_k(const float* __restrict__ P, int T, float* __restrict__ S) {
    int k = blockIdx.x * 256 + threadIdx.x;
    float s = 0.f;
    for (int t = 0; t < T; ++t) s += P[(size_t)t * KPAD + k];
    S[k] = s;
}

// ---------------------------------------------------------------------------
// rowpass: r[k]=1/(1000*Sin[k]); c[b]=1/(12288*dot(E[b,:],r));
// block partial colsum of E[b,k]*c[b] -> Pout[bid][k]  (NO atomics).
// 256 blocks x 48 rows; lane owns fixed 16-col slice.
__global__ __launch_bounds__(256)
void rowpass_k(const f16* __restrict__ E16, const float* __restrict__ Sin,
               float* __restrict__ Pout) {
    __shared__ float rl[KPAD];
    __shared__ float cols4[4][KPAD];
    int tid = threadIdx.x;
    for (int n = tid; n < KPAD; n += 256)
        rl[n] = (n < KDIM) ? 1.0f / (1000.0f * Sin[n]) : 0.0f;
    __syncthreads();
    int wave = tid >> 6, lane = tid & 63;
    int n0 = lane * 16;
    float rv[16];
#pragma unroll
    for (int i = 0; i < 16; ++i) rv[i] = rl[n0 + i];
    float ca[16];
#pragma unroll
    for (int i = 0; i < 16; ++i) ca[i] = 0.f;
    int rowbase = blockIdx.x * 48 + wave * 12;
    for (int j = 0; j < 12; ++j) {
        const f16* er = E16 + (size_t)(rowbase + j) * KPAD + n0;
        f16x8 e0 = *(const f16x8*)er;
        f16x8 e1 = *(const f16x8*)(er + 8);
        float ev[16];
#pragma unroll
        for (int i = 0; i < 8; ++i) { ev[i] = (float)e0[i]; ev[8 + i] = (float)e1[i]; }
        float p = 0.f;
#pragma unroll
        for (int i = 0; i < 16; ++i) p += ev[i] * rv[i];
        p = wsum(p);
        float c = 1.0f / (12288.0f * p);
#pragma unroll
        for (int i = 0; i < 16; ++i) ca[i] += ev[i] * c;
    }
#pragma unroll
    for (int i = 0; i < 16; ++i) {
        int idx = (i + lane) & 15;
        cols4[wave][n0 + idx] = ca[idx];
    }
    __syncthreads();
    for (int n = tid; n < KPAD; n += 256)
        Pout[(size_t)blockIdx.x * KPAD + n] =
            cols4[0][n] + cols4[1][n] + cols4[2][n] + cols4[3][n];
}

// ---------------------------------------------------------------------------
// out[b,:] = E[b,:]*r / dot(E[b,:], r) for rows < 4096
__global__ __launch_bounds__(256)
void out_k(const f16* __restrict__ E16, const float* __restrict__ S2,
           float* __restrict__ out) {
    __shared__ float rl[KPAD];
    int tid = threadIdx.x;
    for (int n = tid; n < KPAD; n += 256)
        rl[n] = (n < KDIM) ? 1.0f / (1000.0f * S2[n]) : 0.0f;
    __syncthreads();
    int wave = tid >> 6, lane = tid & 63;
    int n0 = lane * 16;
    float rv[16];
#pragma unroll
    for (int i = 0; i < 16; ++i) rv[i] = rl[n0 + i];
    int rowbase = blockIdx.x * 8 + wave * 2;
    for (int j = 0; j < 2; ++j) {
        int row = rowbase + j;
        const f16* er = E16 + (size_t)row * KPAD + n0;
        f16x8 e0 = *(const f16x8*)er;
        f16x8 e1 = *(const f16x8*)(er + 8);
        float w[16];
        float p = 0.f;
#pragma unroll
        for (int i = 0; i < 8; ++i) {
            w[i] = (float)e0[i] * rv[i];
            w[8 + i] = (float)e1[i] * rv[8 + i];
        }
#pragma unroll
        for (int i = 0; i < 16; ++i) p += w[i];
        p = wsum(p);
        float inv = 1.0f / p;
        float* orow = out + (size_t)row * KDIM;
#pragma unroll
        for (int i = 0; i < 16; i += 4) {
            int n = n0 + i;
            if (n + 3 < KDIM) {
                float4 o = { w[i] * inv, w[i + 1] * inv, w[i + 2] * inv, w[i + 3] * inv };
                *(float4*)(orow + n) = o;
            } else {
#pragma unroll
                for (int t = 0; t < 4; ++t)
                    if (n + t < KDIM) orow[n + t] = w[i + t] * inv;
            }
        }
    }
}

// ---------------------------------------------------------------------------
extern "C" void kernel_launch(void* const* d_in, const int* in_sizes, int n_in,
                              void* d_out, int out_size, void* d_ws, size_t ws_size,
                              hipStream_t stream) {
    (void)in_sizes; (void)n_in; (void)out_size; (void)ws_size;
    const float* feats = (const float*)d_in[0];   // [4096,256]
    const float* head  = (const float*)d_in[1];   // [256,1000]
    const float* queue = (const float*)d_in[2];   // [8192,256]
    float* out = (float*)d_out;                   // [4096,1000]

    char* ws = (char*)d_ws;
    f16*   A16 = (f16*)(ws + OFF_A16);
    f16*   Bf  = (f16*)(ws + OFF_BF);
    f16*   E16 = (f16*)(ws + OFF_E16);
    float* P0  = (float*)(ws + OFF_P0);
    float* P1  = (float*)(ws + OFF_P1);
    float* P2  = (float*)(ws + OFF_P2);
    float* S   = (float*)(ws + OFF_S);
    float* S0  = S;
    float* S1  = S + KPAD;
    float* S2  = S + 2 * KPAD;

    prep_k<<<3088, 256, 0, stream>>>(feats, queue, head, A16, Bf);
    gemm_exp_k<<<dim3(8, 96), 256, 0, stream>>>(A16, Bf, E16, P0);
    redS_k<<<4, 256, 0, stream>>>(P0, 96, S0);
    rowpass_k<<<256, 256, 0, stream>>>(E16, S0, P1);
    redS_k<<<4, 256, 0, stream>>>(P1, 256, S1);
    rowpass_k<<<256, 256, 0, stream>>>(E16, S1, P2);
    redS_k<<<4, 256, 0, stream>>>(P2, 256, S2);
    out_k<<<NFEAT / 8, 256, 0, stream>>>(E16, S2, out);
}

// Round 7
// 160.576 us; speedup vs baseline: 4.2315x; 1.8740x over previous
//
#include <hip/hip_runtime.h>
#include <math.h>

typedef _Float16 f16;
typedef _Float16 f16x8 __attribute__((ext_vector_type(8)));
typedef _Float16 f16x4 __attribute__((ext_vector_type(4)));
typedef float f32x4 __attribute__((ext_vector_type(4)));

#define NROWS 12288
#define NFEAT 4096
#define DDIM  256
#define KDIM  1000
#define KPAD  1024

// workspace layout (bytes)
static const size_t OFF_A16 = 0;           // 12288*256 f16 = 6,291,456
static const size_t OFF_BF  = 6291456;     // 1024*256 f16  =   524,288
static const size_t OFF_E16 = 6815744;     // 12288*1024 f16= 25,165,824
static const size_t OFF_P0  = 31981568;    // 96*1024 f32   =   393,216
static const size_t OFF_P1  = 32374784;    // 256*1024 f32  = 1,048,576
static const size_t OFF_P2  = 33423360;    // 256*1024 f32  = 1,048,576
static const size_t OFF_S   = 34471936;    // 3*1024 f32

__device__ inline float wsum(float v) {
#pragma unroll
    for (int m = 32; m >= 1; m >>= 1) v += __shfl_xor(v, m, 64);
    return v;
}

// ---------------------------------------------------------------------------
// prep: [0,3072) feats/queue row norms -> A16 (4 rows/block)
//       [3072,3088) head: 16 rows/block -> rinv + transposed f16 Bf
__global__ __launch_bounds__(256)
void prep_k(const float* __restrict__ feats, const float* __restrict__ queue,
            const float* __restrict__ head, f16* __restrict__ A16,
            f16* __restrict__ Bf) {
    int b = blockIdx.x, tid = threadIdx.x;
    int wave = tid >> 6, lane = tid & 63;
    if (b < 3072) {
        int row = b * 4 + wave;
        const float* src = (row < NFEAT) ? feats + (size_t)row * DDIM
                                         : queue + (size_t)(row - NFEAT) * DDIM;
        float4 v = *(const float4*)(src + lane * 4);
        float s = wsum(v.x * v.x + v.y * v.y + v.z * v.z + v.w * v.w);
        float inv = 1.0f / sqrtf(fmaxf(s, 1e-24f));
        f16x4 o = { (f16)(v.x * inv), (f16)(v.y * inv), (f16)(v.z * inv), (f16)(v.w * inv) };
        *(f16x4*)(A16 + (size_t)row * DDIM + lane * 4) = o;
    } else {
        __shared__ float rin[16];
        int kb = (b - 3072) * 16;
        for (int j = 0; j < 4; ++j) {
            int k = kb + wave * 4 + j;
            const float* hr = head + (size_t)k * KDIM;
            float s = 0.f;
            for (int n = lane; n < KDIM; n += 64) { float v = hr[n]; s += v * v; }
            s = wsum(s);
            if (lane == 0) rin[wave * 4 + j] = 1.0f / sqrtf(fmaxf(s, 1e-24f));
        }
        __syncthreads();
        float r[16];
#pragma unroll
        for (int i = 0; i < 16; ++i) r[i] = rin[i];
        for (int n = tid; n < KDIM; n += 256) {
            f16 tmp[16];
#pragma unroll
            for (int i = 0; i < 16; ++i)
                tmp[i] = (f16)(head[(size_t)(kb + i) * KDIM + n] * r[i]);
            f16* dst = Bf + (size_t)n * DDIM + kb;
            *(uint4*)(dst)     = *(const uint4*)(tmp);
            *(uint4*)(dst + 8) = *(const uint4*)(tmp + 8);
        }
    }
}

// ---------------------------------------------------------------------------
// MFMA GEMM + exp + f16 E store + colsum partial -> P0[by][col] (NO atomics).
__global__ __launch_bounds__(256, 3)
void gemm_exp_k(const f16* __restrict__ A16, const f16* __restrict__ Bf,
                f16* __restrict__ E16, float* __restrict__ P0) {
    __shared__ __align__(16) char smem[34816];
    f16 (*Es)[136] = (f16(*)[136])smem;
    int tid = threadIdx.x;
    int wave = tid >> 6, lane = tid & 63;
    int lm = lane & 15, q = lane >> 4;
    int row0 = blockIdx.y * 128, col0 = blockIdx.x * 128;
    int wm = (wave >> 1) * 64, wn = (wave & 1) * 64;
    const f16* Ab = A16 + (size_t)(row0 + wm + lm) * DDIM + q * 8;
    const f16* Bb = Bf  + (size_t)(col0 + wn + lm) * DDIM + q * 8;

    f32x4 acc[4][4];
#pragma unroll
    for (int i = 0; i < 4; ++i)
#pragma unroll
        for (int j = 0; j < 4; ++j) acc[i][j] = (f32x4){0.f, 0.f, 0.f, 0.f};

#pragma unroll
    for (int kt = 0; kt < DDIM; kt += 32) {
        f16x8 a[4], b[4];
#pragma unroll
        for (int ms = 0; ms < 4; ++ms) a[ms] = *(const f16x8*)(Ab + (size_t)ms * 16 * DDIM + kt);
#pragma unroll
        for (int ns = 0; ns < 4; ++ns) b[ns] = *(const f16x8*)(Bb + (size_t)ns * 16 * DDIM + kt);
#pragma unroll
        for (int ms = 0; ms < 4; ++ms)
#pragma unroll
            for (int ns = 0; ns < 4; ++ns)
                acc[ms][ns] = __builtin_amdgcn_mfma_f32_16x16x32_f16(a[ms], b[ns], acc[ms][ns], 0, 0, 0);
    }

    float colp[4] = {0.f, 0.f, 0.f, 0.f};
#pragma unroll
    for (int ms = 0; ms < 4; ++ms) {
#pragma unroll
        for (int ns = 0; ns < 4; ++ns) {
            int gc = col0 + wn + ns * 16 + lm;
            bool ok = gc < KDIM;
#pragma unroll
            for (int r = 0; r < 4; ++r) {
                float e = ok ? __expf(acc[ms][ns][r] * 20.0f) : 0.0f;
                colp[ns] += e;
                Es[wm + ms * 16 + q * 4 + r][wn + ns * 16 + lm] = (f16)e;
            }
        }
    }
    // sum over q (rows within the wave's 64-row half)
#pragma unroll
    for (int ns = 0; ns < 4; ++ns) {
        colp[ns] += __shfl_xor(colp[ns], 16, 64);
        colp[ns] += __shfl_xor(colp[ns], 32, 64);
    }
    __syncthreads();
    // coalesced f16 store of the block's 128x128 tile
    {
        int r = tid >> 1, half = tid & 1;
        const f16* src = &Es[r][half * 64];
        f16* dst = E16 + (size_t)(row0 + r) * KPAD + col0 + half * 64;
#pragma unroll
        for (int i = 0; i < 8; ++i)
            *(uint4*)(dst + i * 8) = *(const uint4*)(src + i * 8);
    }
    __syncthreads();            // all Es reads done; reuse smem for colsum
    float* cred = (float*)smem; // 128 floats
    if (tid < 128) cred[tid] = 0.f;
    __syncthreads();
    if (lane < 16) {
#pragma unroll
        for (int ns = 0; ns < 4; ++ns)
            atomicAdd(&cred[wn + ns * 16 + lane], colp[ns]);   // LDS atomic, 2-deep
    }
    __syncthreads();
    if (tid < 128) P0[(size_t)blockIdx.y * KPAD + col0 + tid] = cred[tid];
}

// ---------------------------------------------------------------------------
// redS: S[k] = sum_{t<T} P[t*KPAD + k]. Compile-time T -> fully unrolled,
// independent loads in flight. 64 blocks x 256 threads: 16 tgroups x 16 cols.
template <int T>
__global__ __launch_bounds__(256)
void redS_k(const float* __restrict__ P, float* __restrict__ S) {
    __shared__ float sh[16][17];
    int tid = threadIdx.x;
    int c = tid & 15, tg = tid >> 4;
    int col = blockIdx.x * 16 + c;
    constexpr int PER = T / 16;          // 6 or 16
    float s = 0.f;
#pragma unroll
    for (int i = 0; i < PER; ++i)
        s += P[(size_t)(tg * PER + i) * KPAD + col];
    sh[tg][c] = s;
    __syncthreads();
    if (tid < 16) {
        float t = 0.f;
#pragma unroll
        for (int g = 0; g < 16; ++g) t += sh[g][tid];
        S[blockIdx.x * 16 + tid] = t;
    }
}

// ---------------------------------------------------------------------------
// rowpass: r[k]=1/(1000*Sin[k]); c[b]=1/(12288*dot(E[b,:],r));
// block partial colsum of E[b,k]*c[b] -> Pout[bid][k]  (NO atomics).
// 256 blocks x 48 rows; lane owns fixed 16-col slice.
__global__ __launch_bounds__(256)
void rowpass_k(const f16* __restrict__ E16, const float* __restrict__ Sin,
               float* __restrict__ Pout) {
    __shared__ float rl[KPAD];
    __shared__ float cols4[4][KPAD];
    int tid = threadIdx.x;
    for (int n = tid; n < KPAD; n += 256)
        rl[n] = (n < KDIM) ? 1.0f / (1000.0f * Sin[n]) : 0.0f;
    __syncthreads();
    int wave = tid >> 6, lane = tid & 63;
    int n0 = lane * 16;
    float rv[16];
#pragma unroll
    for (int i = 0; i < 16; ++i) rv[i] = rl[n0 + i];
    float ca[16];
#pragma unroll
    for (int i = 0; i < 16; ++i) ca[i] = 0.f;
    int rowbase = blockIdx.x * 48 + wave * 12;
    for (int j = 0; j < 12; ++j) {
        const f16* er = E16 + (size_t)(rowbase + j) * KPAD + n0;
        f16x8 e0 = *(const f16x8*)er;
        f16x8 e1 = *(const f16x8*)(er + 8);
        float ev[16];
#pragma unroll
        for (int i = 0; i < 8; ++i) { ev[i] = (float)e0[i]; ev[8 + i] = (float)e1[i]; }
        float p = 0.f;
#pragma unroll
        for (int i = 0; i < 16; ++i) p += ev[i] * rv[i];
        p = wsum(p);
        float c = 1.0f / (12288.0f * p);
#pragma unroll
        for (int i = 0; i < 16; ++i) ca[i] += ev[i] * c;
    }
#pragma unroll
    for (int i = 0; i < 16; ++i) {
        int idx = (i + lane) & 15;
        cols4[wave][n0 + idx] = ca[idx];
    }
    __syncthreads();
    for (int n = tid; n < KPAD; n += 256)
        Pout[(size_t)blockIdx.x * KPAD + n] =
            cols4[0][n] + cols4[1][n] + cols4[2][n] + cols4[3][n];
}

// ---------------------------------------------------------------------------
// out[b,:] = E[b,:]*r / dot(E[b,:], r) for rows < 4096
__global__ __launch_bounds__(256)
void out_k(const f16* __restrict__ E16, const float* __restrict__ S2,
           float* __restrict__ out) {
    __shared__ float rl[KPAD];
    int tid = threadIdx.x;
    for (int n = tid; n < KPAD; n += 256)
        rl[n] = (n < KDIM) ? 1.0f / (1000.0f * S2[n]) : 0.0f;
    __syncthreads();
    int wave = tid >> 6, lane = tid & 63;
    int n0 = lane * 16;
    float rv[16];
#pragma unroll
    for (int i = 0; i < 16; ++i) rv[i] = rl[n0 + i];
    int rowbase = blockIdx.x * 8 + wave * 2;
    for (int j = 0; j < 2; ++j) {
        int row = rowbase + j;
        const f16* er = E16 + (size_t)row * KPAD + n0;
        f16x8 e0 = *(const f16x8*)er;
        f16x8 e1 = *(const f16x8*)(er + 8);
        float w[16];
        float p = 0.f;
#pragma unroll
        for (int i = 0; i < 8; ++i) {
            w[i] = (float)e0[i] * rv[i];
            w[8 + i] = (float)e1[i] * rv[8 + i];
        }
#pragma unroll
        for (int i = 0; i < 16; ++i) p += w[i];
        p = wsum(p);
        float inv = 1.0f / p;
        float* orow = out + (size_t)row * KDIM;
#pragma unroll
        for (int i = 0; i < 16; i += 4) {
            int n = n0 + i;
            if (n + 3 < KDIM) {
                float4 o = { w[i] * inv, w[i + 1] * inv, w[i + 2] * inv, w[i + 3] * inv };
                *(float4*)(orow + n) = o;
            } else {
#pragma unroll
                for (int t = 0; t < 4; ++t)
                    if (n + t < KDIM) orow[n + t] = w[i + t] * inv;
            }
        }
    }
}

// ---------------------------------------------------------------------------
extern "C" void kernel_launch(void* const* d_in, const int* in_sizes, int n_in,
                              void* d_out, int out_size, void* d_ws, size_t ws_size,
                              hipStream_t stream) {
    (void)in_sizes; (void)n_in; (void)out_size; (void)ws_size;
    const float* feats = (const float*)d_in[0];   // [4096,256]
    const float* head  = (const float*)d_in[1];   // [256,1000]
    const float* queue = (const float*)d_in[2];   // [8192,256]
    float* out = (float*)d_out;                   // [4096,1000]

    char* ws = (char*)d_ws;
    f16*   A16 = (f16*)(ws + OFF_A16);
    f16*   Bf  = (f16*)(ws + OFF_BF);
    f16*   E16 = (f16*)(ws + OFF_E16);
    float* P0  = (float*)(ws + OFF_P0);
    float* P1  = (float*)(ws + OFF_P1);
    float* P2  = (float*)(ws + OFF_P2);
    float* S   = (float*)(ws + OFF_S);
    float* S0  = S;
    float* S1  = S + KPAD;
    float* S2  = S + 2 * KPAD;

    prep_k<<<3088, 256, 0, stream>>>(feats, queue, head, A16, Bf);
    gemm_exp_k<<<dim3(8, 96), 256, 0, stream>>>(A16, Bf, E16, P0);
    redS_k<96><<<64, 256, 0, stream>>>(P0, S0);
    rowpass_k<<<256, 256, 0, stream>>>(E16, S0, P1);
    redS_k<256><<<64, 256, 0, stream>>>(P1, S1);
    rowpass_k<<<256, 256, 0, stream>>>(E16, S1, P2);
    redS_k<256><<<64, 256, 0, stream>>>(P2, S2);
    out_k<<<NFEAT / 8, 256, 0, stream>>>(E16, S2, out);
}

// Round 8
// 150.501 us; speedup vs baseline: 4.5148x; 1.0669x over previous
//
#include <hip/hip_runtime.h>
#include <math.h>

typedef _Float16 f16;
typedef _Float16 f16x8 __attribute__((ext_vector_type(8)));
typedef _Float16 f16x4 __attribute__((ext_vector_type(4)));
typedef float f32x4 __attribute__((ext_vector_type(4)));

#define NROWS 12288
#define NFEAT 4096
#define DDIM  256
#define KDIM  1000
#define KPAD  1024

// workspace layout (bytes)
static const size_t OFF_A16 = 0;           // 12288*256 f16 = 6,291,456
static const size_t OFF_BF  = 6291456;     // 1024*256 f16  =   524,288
static const size_t OFF_E16 = 6815744;     // 12288*1024 f16= 25,165,824
static const size_t OFF_P0  = 31981568;    // 96*1024 f32   =   393,216
static const size_t OFF_P1  = 32374784;    // 768*1024 f32  = 3,145,728
static const size_t OFF_P2  = 35520512;    // 768*1024 f32  = 3,145,728
static const size_t OFF_S   = 38666240;    // 3*1024 f32

__device__ inline float wsum(float v) {
#pragma unroll
    for (int m = 32; m >= 1; m >>= 1) v += __shfl_xor(v, m, 64);
    return v;
}

// ---------------------------------------------------------------------------
// prep: [0,3072) feats/queue row norms -> A16 (4 rows/block)
//       [3072,3104) head: 8 k-rows/block -> rinv + transposed f16 Bf
__global__ __launch_bounds__(256)
void prep_k(const float* __restrict__ feats, const float* __restrict__ queue,
            const float* __restrict__ head, f16* __restrict__ A16,
            f16* __restrict__ Bf) {
    int b = blockIdx.x, tid = threadIdx.x;
    int wave = tid >> 6, lane = tid & 63;
    if (b < 3072) {
        int row = b * 4 + wave;
        const float* src = (row < NFEAT) ? feats + (size_t)row * DDIM
                                         : queue + (size_t)(row - NFEAT) * DDIM;
        float4 v = *(const float4*)(src + lane * 4);
        float s = wsum(v.x * v.x + v.y * v.y + v.z * v.z + v.w * v.w);
        float inv = 1.0f / sqrtf(fmaxf(s, 1e-24f));
        f16x4 o = { (f16)(v.x * inv), (f16)(v.y * inv), (f16)(v.z * inv), (f16)(v.w * inv) };
        *(f16x4*)(A16 + (size_t)row * DDIM + lane * 4) = o;
    } else {
        __shared__ float rin[8];
        int kb = (b - 3072) * 8;
        for (int j = 0; j < 2; ++j) {
            int k = kb + wave * 2 + j;
            const float* hr = head + (size_t)k * KDIM;
            float s = 0.f;
            for (int n = lane; n < KDIM; n += 64) { float v = hr[n]; s += v * v; }
            s = wsum(s);
            if (lane == 0) rin[wave * 2 + j] = 1.0f / sqrtf(fmaxf(s, 1e-24f));
        }
        __syncthreads();
        float r[8];
#pragma unroll
        for (int i = 0; i < 8; ++i) r[i] = rin[i];
        for (int n = tid; n < KDIM; n += 256) {
            f16 tmp[8];
#pragma unroll
            for (int i = 0; i < 8; ++i)
                tmp[i] = (f16)(head[(size_t)(kb + i) * KDIM + n] * r[i]);
            *(uint4*)(Bf + (size_t)n * DDIM + kb) = *(const uint4*)(tmp);
        }
    }
}

// ---------------------------------------------------------------------------
// MFMA GEMM + exp + f16 E store + colsum partial -> P0[by][col] (NO atomics).
__global__ __launch_bounds__(256, 3)
void gemm_exp_k(const f16* __restrict__ A16, const f16* __restrict__ Bf,
                f16* __restrict__ E16, float* __restrict__ P0) {
    __shared__ __align__(16) char smem[34816];
    f16 (*Es)[136] = (f16(*)[136])smem;
    int tid = threadIdx.x;
    int wave = tid >> 6, lane = tid & 63;
    int lm = lane & 15, q = lane >> 4;
    int row0 = blockIdx.y * 128, col0 = blockIdx.x * 128;
    int wm = (wave >> 1) * 64, wn = (wave & 1) * 64;
    const f16* Ab = A16 + (size_t)(row0 + wm + lm) * DDIM + q * 8;
    const f16* Bb = Bf  + (size_t)(col0 + wn + lm) * DDIM + q * 8;

    f32x4 acc[4][4];
#pragma unroll
    for (int i = 0; i < 4; ++i)
#pragma unroll
        for (int j = 0; j < 4; ++j) acc[i][j] = (f32x4){0.f, 0.f, 0.f, 0.f};

#pragma unroll
    for (int kt = 0; kt < DDIM; kt += 32) {
        f16x8 a[4], b[4];
#pragma unroll
        for (int ms = 0; ms < 4; ++ms) a[ms] = *(const f16x8*)(Ab + (size_t)ms * 16 * DDIM + kt);
#pragma unroll
        for (int ns = 0; ns < 4; ++ns) b[ns] = *(const f16x8*)(Bb + (size_t)ns * 16 * DDIM + kt);
#pragma unroll
        for (int ms = 0; ms < 4; ++ms)
#pragma unroll
            for (int ns = 0; ns < 4; ++ns)
                acc[ms][ns] = __builtin_amdgcn_mfma_f32_16x16x32_f16(a[ms], b[ns], acc[ms][ns], 0, 0, 0);
    }

    float colp[4] = {0.f, 0.f, 0.f, 0.f};
#pragma unroll
    for (int ms = 0; ms < 4; ++ms) {
#pragma unroll
        for (int ns = 0; ns < 4; ++ns) {
            int gc = col0 + wn + ns * 16 + lm;
            bool ok = gc < KDIM;
#pragma unroll
            for (int r = 0; r < 4; ++r) {
                float e = ok ? __expf(acc[ms][ns][r] * 20.0f) : 0.0f;
                colp[ns] += e;
                Es[wm + ms * 16 + q * 4 + r][wn + ns * 16 + lm] = (f16)e;
            }
        }
    }
    // sum over q (rows within the wave's 64-row half)
#pragma unroll
    for (int ns = 0; ns < 4; ++ns) {
        colp[ns] += __shfl_xor(colp[ns], 16, 64);
        colp[ns] += __shfl_xor(colp[ns], 32, 64);
    }
    __syncthreads();
    // coalesced f16 store of the block's 128x128 tile
    {
        int r = tid >> 1, half = tid & 1;
        const f16* src = &Es[r][half * 64];
        f16* dst = E16 + (size_t)(row0 + r) * KPAD + col0 + half * 64;
#pragma unroll
        for (int i = 0; i < 8; ++i)
            *(uint4*)(dst + i * 8) = *(const uint4*)(src + i * 8);
    }
    __syncthreads();            // all Es reads done; reuse smem for colsum
    float* cred = (float*)smem; // 128 floats
    if (tid < 128) cred[tid] = 0.f;
    __syncthreads();
    if (lane < 16) {
#pragma unroll
        for (int ns = 0; ns < 4; ++ns)
            atomicAdd(&cred[wn + ns * 16 + lane], colp[ns]);   // LDS atomic, 2-deep
    }
    __syncthreads();
    if (tid < 128) P0[(size_t)blockIdx.y * KPAD + col0 + tid] = cred[tid];
}

// ---------------------------------------------------------------------------
// redS: S[k] = sum_{t<T} P[t*KPAD + k]. Compile-time T -> fully unrolled,
// independent loads in flight. 64 blocks x 256 threads: 16 tgroups x 16 cols.
template <int T>
__global__ __launch_bounds__(256)
void redS_k(const float* __restrict__ P, float* __restrict__ S) {
    __shared__ float sh[16][17];
    int tid = threadIdx.x;
    int c = tid & 15, tg = tid >> 4;
    int col = blockIdx.x * 16 + c;
    constexpr int PER = T / 16;
    float s = 0.f;
#pragma unroll
    for (int i = 0; i < PER; ++i)
        s += P[(size_t)(tg * PER + i) * KPAD + col];
    sh[tg][c] = s;
    __syncthreads();
    if (tid < 16) {
        float t = 0.f;
#pragma unroll
        for (int g = 0; g < 16; ++g) t += sh[g][tid];
        S[blockIdx.x * 16 + tid] = t;
    }
}

// ---------------------------------------------------------------------------
// rowpass: r[k]=1/(1000*Sin[k]); c[b]=1/(12288*dot(E[b,:],r));
// block partial colsum of E[b,k]*c[b] -> Pout[bid][k]  (NO atomics).
// 768 blocks x 16 rows (3 blocks/CU); lane owns fixed 16-col slice.
__global__ __launch_bounds__(256)
void rowpass_k(const f16* __restrict__ E16, const float* __restrict__ Sin,
               float* __restrict__ Pout) {
    __shared__ float rl[KPAD];
    __shared__ float cols4[4][KPAD];
    int tid = threadIdx.x;
    for (int n = tid; n < KPAD; n += 256)
        rl[n] = (n < KDIM) ? 1.0f / (1000.0f * Sin[n]) : 0.0f;
    __syncthreads();
    int wave = tid >> 6, lane = tid & 63;
    int n0 = lane * 16;
    float rv[16];
#pragma unroll
    for (int i = 0; i < 16; ++i) rv[i] = rl[n0 + i];
    float ca[16];
#pragma unroll
    for (int i = 0; i < 16; ++i) ca[i] = 0.f;
    int rowbase = blockIdx.x * 16 + wave * 4;
#pragma unroll
    for (int j = 0; j < 4; ++j) {
        const f16* er = E16 + (size_t)(rowbase + j) * KPAD + n0;
        f16x8 e0 = *(const f16x8*)er;
        f16x8 e1 = *(const f16x8*)(er + 8);
        float ev[16];
#pragma unroll
        for (int i = 0; i < 8; ++i) { ev[i] = (float)e0[i]; ev[8 + i] = (float)e1[i]; }
        float p = 0.f;
#pragma unroll
        for (int i = 0; i < 16; ++i) p += ev[i] * rv[i];
        p = wsum(p);
        float c = 1.0f / (12288.0f * p);
#pragma unroll
        for (int i = 0; i < 16; ++i) ca[i] += ev[i] * c;
    }
#pragma unroll
    for (int i = 0; i < 16; ++i) {
        int idx = (i + lane) & 15;
        cols4[wave][n0 + idx] = ca[idx];
    }
    __syncthreads();
    for (int n = tid; n < KPAD; n += 256)
        Pout[(size_t)blockIdx.x * KPAD + n] =
            cols4[0][n] + cols4[1][n] + cols4[2][n] + cols4[3][n];
}

// ---------------------------------------------------------------------------
// out[b,:] = E[b,:]*r / dot(E[b,:], r) for rows < 4096. 1 row per wave.
__global__ __launch_bounds__(256)
void out_k(const f16* __restrict__ E16, const float* __restrict__ S2,
           float* __restrict__ out) {
    __shared__ float rl[KPAD];
    int tid = threadIdx.x;
    for (int n = tid; n < KPAD; n += 256)
        rl[n] = (n < KDIM) ? 1.0f / (1000.0f * S2[n]) : 0.0f;
    __syncthreads();
    int wave = tid >> 6, lane = tid & 63;
    int n0 = lane * 16;
    float rv[16];
#pragma unroll
    for (int i = 0; i < 16; ++i) rv[i] = rl[n0 + i];
    int row = blockIdx.x * 4 + wave;
    const f16* er = E16 + (size_t)row * KPAD + n0;
    f16x8 e0 = *(const f16x8*)er;
    f16x8 e1 = *(const f16x8*)(er + 8);
    float w[16];
    float p = 0.f;
#pragma unroll
    for (int i = 0; i < 8; ++i) {
        w[i] = (float)e0[i] * rv[i];
        w[8 + i] = (float)e1[i] * rv[8 + i];
    }
#pragma unroll
    for (int i = 0; i < 16; ++i) p += w[i];
    p = wsum(p);
    float inv = 1.0f / p;
    float* orow = out + (size_t)row * KDIM;
#pragma unroll
    for (int i = 0; i < 16; i += 4) {
        int n = n0 + i;
        if (n + 3 < KDIM) {
            float4 o = { w[i] * inv, w[i + 1] * inv, w[i + 2] * inv, w[i + 3] * inv };
            *(float4*)(orow + n) = o;
        } else {
#pragma unroll
            for (int t = 0; t < 4; ++t)
                if (n + t < KDIM) orow[n + t] = w[i + t] * inv;
        }
    }
}

// ---------------------------------------------------------------------------
extern "C" void kernel_launch(void* const* d_in, const int* in_sizes, int n_in,
                              void* d_out, int out_size, void* d_ws, size_t ws_size,
                              hipStream_t stream) {
    (void)in_sizes; (void)n_in; (void)out_size; (void)ws_size;
    const float* feats = (const float*)d_in[0];   // [4096,256]
    const float* head  = (const float*)d_in[1];   // [256,1000]
    const float* queue = (const float*)d_in[2];   // [8192,256]
    float* out = (float*)d_out;                   // [4096,1000]

    char* ws = (char*)d_ws;
    f16*   A16 = (f16*)(ws + OFF_A16);
    f16*   Bf  = (f16*)(ws + OFF_BF);
    f16*   E16 = (f16*)(ws + OFF_E16);
    float* P0  = (float*)(ws + OFF_P0);
    float* P1  = (float*)(ws + OFF_P1);
    float* P2  = (float*)(ws + OFF_P2);
    float* S   = (float*)(ws + OFF_S);
    float* S0  = S;
    float* S1  = S + KPAD;
    float* S2  = S + 2 * KPAD;

    prep_k<<<3104, 256, 0, stream>>>(feats, queue, head, A16, Bf);
    gemm_exp_k<<<dim3(8, 96), 256, 0, stream>>>(A16, Bf, E16, P0);
    redS_k<96><<<64, 256, 0, stream>>>(P0, S0);
    rowpass_k<<<768, 256, 0, stream>>>(E16, S0, P1);
    redS_k<768><<<64, 256, 0, stream>>>(P1, S1);
    rowpass_k<<<768, 256, 0, stream>>>(E16, S1, P2);
    redS_k<768><<<64, 256, 0, stream>>>(P2, S2);
    out_k<<<NFEAT / 4, 256, 0, stream>>>(E16, S2, out);
}